// Round 5
// baseline (619.334 us; speedup 1.0000x reference)
//
#include <hip/hip_runtime.h>
#include <hip/hip_bf16.h>

#define CIN   64
#define COUT  64
#define TT    512
#define FF    161
#define KTOT  576          // 9 * 64
#define TFSTR (TT*FF)      // 82432
#define FP_   168          // padded f dim of X2: fp = f+1, zeros at fp=0 and fp>=162

#define W2_BYTES ((size_t)FF*COUT*KTOT*2)            // 11,870,208
#define X2_BYTES ((size_t)8*TT*FP_*64*2)             // 88,080,384
#define PW_BLOCKS 5796                               // 161*9216/256 u16x4 quads

typedef __bf16 bf16x8 __attribute__((ext_vector_type(8)));
typedef float  f32x4  __attribute__((ext_vector_type(4)));
typedef unsigned short u16x8 __attribute__((ext_vector_type(8)));
typedef unsigned short u16x4 __attribute__((ext_vector_type(4)));
typedef float f4u __attribute__((ext_vector_type(4), aligned(4)));
typedef float f2u __attribute__((ext_vector_type(2), aligned(4)));

__device__ __forceinline__ unsigned short f2bf(float v) {
    union { float f; unsigned int u; } c; c.f = v;
    unsigned int u = c.u + 0x7FFFu + ((c.u >> 16) & 1u);   // RNE
    return (unsigned short)(u >> 16);
}

// ---- fused prep: blocks [0, PW_BLOCKS) repack weights; rest transpose x ----
__global__ __launch_bounds__(256) void prep_fused(
    const float* __restrict__ ksrc, unsigned short* __restrict__ w2,
    const float* __restrict__ x, unsigned short* __restrict__ x2)
{
    __shared__ unsigned short Xs[64][170];
    int bx = blockIdx.x;
    int tid = threadIdx.x;

    if (bx < PW_BLOCKS) {
        int g  = bx*256 + tid;          // u16x4 index
        int f  = g / 9216;
        int j  = g - f*9216;
        int o  = j / 144;
        int r  = j - o*144;
        int q  = r >> 4;                // tap
        int i4 = (r & 15) * 4;
        u16x4 v;
        #pragma unroll
        for (int e = 0; e < 4; ++e)
            v[e] = f2bf(ksrc[((size_t)(o*64 + i4 + e)*FF + f)*9 + q]);
        *(u16x4*)&w2[(size_t)f*36864 + j*4] = v;
        return;
    }

    int bt = bx - PW_BLOCKS;            // 0..4095
    int b  = bt >> 9;
    int t  = bt & 511;
    const float* xb = x + (size_t)b*CIN*TFSTR + (size_t)t*FF;
    #pragma unroll
    for (int k = 0; k < 21; ++k) {
        int s = tid + k*256;
        if (s < 5184) {                 // 64 i * 81 slots
            int i = s / 81;
            int u = s - i*81;
            const float* p = xb + (size_t)i*TFSTR + 2*u;
            if (u < 80) {
                f2u v = *(const f2u*)p;
                unsigned pk = (unsigned)f2bf(v.x) | ((unsigned)f2bf(v.y) << 16);
                *(unsigned*)&Xs[i][2*u] = pk;
            } else {
                Xs[i][160] = f2bf(*p);
            }
        }
    }
    __syncthreads();
    unsigned short* ob = x2 + (size_t)bt * FP_ * 64;
    #pragma unroll
    for (int k = 0; k < 6; ++k) {
        int s = tid + k*256;
        if (s < 1344) {                 // 168 fp rows * 8 chunks
            int fp = s >> 3;
            int j  = s & 7;
            u16x8 v = {0,0,0,0,0,0,0,0};
            if (fp >= 1 && fp < 162) {
                int f = fp - 1;
                #pragma unroll
                for (int e = 0; e < 8; ++e) v[e] = Xs[j*8 + e][f];
            }
            *(u16x8*)&ob[fp*64 + j*8] = v;
        }
    }
}

// ---- main: block = 64t x 64o x 16f (4 chunks of 4f), 4 waves = o-quarters ----
// Same-stage structure as round-3 kernel (proven 2.75 blocks/CU vehicle); the
// f-loop makes each output line's 4x16B quarters come from ONE block within
// ~3 chunk periods -> completes in L2 before eviction (kills partial-line RMW).
__global__ __launch_bounds__(256, 2) void conv_mfma5(
    const unsigned short* __restrict__ x2, const unsigned short* __restrict__ w2,
    const float* __restrict__ bias, float* __restrict__ out)
{
    int bx = blockIdx.x;            // 704 = 8 * 88
    int b  = bx & 7;                // XCD = batch
    int s  = bx >> 3;               // 0..87
    int tq = s / 11;
    int fg = s - tq*11;             // fg-inner: co-resident blocks share x2[b,tq]
    int t0 = tq * 64;
    int fG = fg * 16;

    // LDS rows = tl*6 + fpl (tl 0..65 +pad, fpl 0..5), 64 bf16 (128B) per row
    __shared__ alignas(16) unsigned short As[416*64];   // 53,248 B

    int tid = threadIdx.x;
    int wv  = tid >> 6;
    int l   = tid & 63;
    int lr  = l >> 3;
    int j   = l & 7;
    int l15 = l & 15;
    int lq  = l >> 4;
    int o   = wv*16 + l15;

    const unsigned short* zrow = x2 + 167*64;   // guaranteed-zero row

    f32x4 acc[4][4];                 // [u=f][mf]

    for (int c = 0; c < 4; ++c) {
        int f0c = fG + c*4;
        if (f0c > 160) break;        // block-uniform (fg=10 runs 1 chunk)

        if (c) __syncthreads();      // all waves done reading previous chunk

        // ---- stage fp = f0c .. f0c+5 (6 rows x 66 tl, 8 slots XOR-swizzled) ----
        #pragma unroll
        for (int it = 0; it < 13; ++it) {
            int r0  = wv*8 + it*32;                 // wave-uniform LDS row base
            int row = r0 + lr;                      // 0..415
            int tl  = row / 6;
            int fpl = row - tl*6;
            int gt  = t0 - 1 + tl;
            int fp  = f0c + fpl;                    // <= 165 < FP_
            bool ok = (tl < 66) && (gt >= 0) && (gt < TT);
            int key = (tl + fpl) & 7;
            const unsigned short* src = ok
                ? x2 + ((((size_t)b*TT + gt)*FP_ + fp)*64 + ((j ^ key) * 8))
                : zrow + j*8;
            __builtin_amdgcn_global_load_lds(
                (const __attribute__((address_space(1))) void*)src,
                (__attribute__((address_space(3))) void*)(As + (size_t)r0*64),
                16, 0, 0);
        }
        __syncthreads();

        // ---- compute 4f x 16o x 64t ----
        #pragma unroll
        for (int u = 0; u < 4; ++u)
            #pragma unroll
            for (int mf = 0; mf < 4; ++mf)
                acc[u][mf] = (f32x4){0.f, 0.f, 0.f, 0.f};

        const unsigned short* wb[4];
        #pragma unroll
        for (int u = 0; u < 4; ++u) {
            int fe = f0c + u; if (fe > 160) fe = 160;     // clamp (discarded)
            wb[u] = w2 + ((size_t)fe*COUT + o)*KTOT;
        }

        #pragma unroll
        for (int dm = 0; dm < 3; ++dm) {
            #pragma unroll
            for (int is = 0; is < 2; ++is) {
                int kb = is*32 + lq*8;
                bf16x8 bw[3][4];
                #pragma unroll
                for (int dn = 0; dn < 3; ++dn)
                    #pragma unroll
                    for (int u = 0; u < 4; ++u)
                        bw[dn][u] = *(const bf16x8*)&wb[u][(dm*3 + dn)*64 + kb];
                #pragma unroll
                for (int mf = 0; mf < 4; ++mf) {
                    int tl = mf*16 + l15 + dm;
                    bf16x8 a6[6];
                    #pragma unroll
                    for (int v = 0; v < 6; ++v) {
                        int isw = kb ^ (((tl + v) & 7) << 3);
                        a6[v] = *(const bf16x8*)&As[(tl*6 + v)*64 + isw];
                    }
                    #pragma unroll
                    for (int dn = 0; dn < 3; ++dn)
                        #pragma unroll
                        for (int u = 0; u < 4; ++u)
                            acc[u][mf] = __builtin_amdgcn_mfma_f32_16x16x32_bf16(
                                a6[u + dn], bw[dn][u], acc[u][mf], 0, 0, 0);
                }
            }
        }

        // ---- epilogue: bias + 16B f-contiguous stores ----
        size_t rowb = ((size_t)b*COUT + o)*TT + t0;
        if (f0c + 3 <= 160) {
            float bv[4];
            #pragma unroll
            for (int u = 0; u < 4; ++u) bv[u] = bias[o*FF + f0c + u];
            #pragma unroll
            for (int mf = 0; mf < 4; ++mf)
                #pragma unroll
                for (int rr = 0; rr < 4; ++rr) {
                    int t = mf*16 + lq*4 + rr;
                    f4u v = { acc[0][mf][rr] + bv[0], acc[1][mf][rr] + bv[1],
                              acc[2][mf][rr] + bv[2], acc[3][mf][rr] + bv[3] };
                    *(f4u*)(out + (rowb + t)*FF + f0c) = v;
                }
        } else {                      // fg=10: only f=160 valid
            float bv0 = bias[o*FF + 160];
            #pragma unroll
            for (int mf = 0; mf < 4; ++mf)
                #pragma unroll
                for (int rr = 0; rr < 4; ++rr) {
                    int t = mf*16 + lq*4 + rr;
                    out[(rowb + t)*FF + 160] = acc[0][mf][rr] + bv0;
                }
        }
    }
}

// ---------------- round-1 fallback (stages directly from f32 x; needs only w2) ----------------
__global__ __launch_bounds__(256) void conv_mfma(
    const float* __restrict__ x, const unsigned short* __restrict__ w2,
    const float* __restrict__ bias, float* __restrict__ out)
{
    int bx = blockIdx.x;
    int r  = bx & 7;
    int q  = bx >> 3;
    int fblk = q % 41;
    int g  = (q / 41) * 8 + r;
    int b  = g >> 3;
    int t0 = (g & 7) * 64;
    int f0 = fblk * 4;

    __shared__ unsigned short Bs[6][66][64];
    int tid = threadIdx.x;

    for (int i = 0; i < 64; i += 4) {
        #pragma unroll
        for (int pp = 0; pp < 2; ++pp) {
            int p = tid + pp*256;
            if (p < 396) {
                int tl = p / 6, fl = p % 6;
                int gt = t0 - 1 + tl;
                int gf = f0 - 1 + fl;
                bool ok = (gt >= 0) && (gt < TT) && (gf >= 0) && (gf < FF);
                const float* xp = x + (((size_t)(b*CIN + i)*TT + gt)*FF + gf);
                float v0 = ok ? xp[0]       : 0.f;
                float v1 = ok ? xp[TFSTR]   : 0.f;
                float v2 = ok ? xp[2*TFSTR] : 0.f;
                float v3 = ok ? xp[3*TFSTR] : 0.f;
                int isw = i ^ (((tl + fl) & 7) << 3);
                ushort4 pk;
                pk.x = f2bf(v0); pk.y = f2bf(v1); pk.z = f2bf(v2); pk.w = f2bf(v3);
                *reinterpret_cast<ushort4*>(&Bs[fl][tl][isw]) = pk;
            }
        }
    }
    __syncthreads();

    int wv = tid >> 6;
    int l  = tid & 63;
    int f  = f0 + wv;
    if (f >= FF) return;

    int l15 = l & 15;
    int lq  = l >> 4;
    f32x4 acc[4][4] = {};
    const unsigned short* wb = w2 + (size_t)f * (COUT * KTOT);

    #pragma unroll
    for (int dm = 0; dm < 3; ++dm)
    #pragma unroll
    for (int dn = 0; dn < 3; ++dn) {
        int fl = wv + dn;
        int kq = (dm*3 + dn) * 64;
        #pragma unroll
        for (int is = 0; is < 2; ++is) {
            int i0 = is*32 + lq*8;
            bf16x8 a[4];
            #pragma unroll
            for (int mf = 0; mf < 4; ++mf) {
                int tl  = mf*16 + l15 + dm;
                int isw = i0 ^ (((tl + fl) & 7) << 3);
                a[mf] = *(const bf16x8*)&Bs[fl][tl][isw];
            }
            int kb = kq + i0;
            #pragma unroll
            for (int nf = 0; nf < 4; ++nf) {
                bf16x8 bfr = *(const bf16x8*)&wb[(size_t)(nf*16 + l15) * KTOT + kb];
                #pragma unroll
                for (int mf = 0; mf < 4; ++mf)
                    acc[mf][nf] = __builtin_amdgcn_mfma_f32_16x16x32_bf16(
                        a[mf], bfr, acc[mf][nf], 0, 0, 0);
            }
        }
    }

    #pragma unroll
    for (int nf = 0; nf < 4; ++nf) {
        int o = nf*16 + l15;
        float bv = bias[o*FF + f];
        size_t obase = (((size_t)b*COUT + o)*TT + t0 + lq*4)*FF + f;
        #pragma unroll
        for (int mf = 0; mf < 4; ++mf)
            #pragma unroll
            for (int rr = 0; rr < 4; ++rr)
                out[obase + (size_t)(mf*16 + rr)*FF] = acc[mf][nf][rr] + bv;
    }
}

extern "C" void kernel_launch(void* const* d_in, const int* in_sizes, int n_in,
                              void* d_out, int out_size, void* d_ws, size_t ws_size,
                              hipStream_t stream)
{
    (void)in_sizes; (void)n_in; (void)out_size;
    const float* x    = (const float*)d_in[0];
    const float* k    = (const float*)d_in[1];
    const float* bias = (const float*)d_in[2];
    float* out = (float*)d_out;
    unsigned short* w2 = (unsigned short*)d_ws;

    bool big = (ws_size >= W2_BYTES + X2_BYTES);
    unsigned short* x2 = (unsigned short*)((char*)d_ws + W2_BYTES);

    prep_fused<<<big ? (PW_BLOCKS + 8*TT) : PW_BLOCKS, 256, 0, stream>>>(k, w2, x, x2);

    if (big) {
        conv_mfma5<<<704, 256, 0, stream>>>(x2, w2, bias, out);     // ~2.75 blocks/CU
    } else {
        conv_mfma<<<8*41*8, 256, 0, stream>>>(x, w2, bias, out);    // fallback
    }
}

// Round 6
// 319.511 us; speedup vs baseline: 1.9384x; 1.9384x over previous
//
#include <hip/hip_runtime.h>
#include <hip/hip_bf16.h>

#define CIN   64
#define COUT  64
#define TT    512
#define FF    161
#define KTOT  576          // 9 * 64
#define TFSTR (TT*FF)      // 82432
#define FP_   168          // padded f dim of X2: fp = f+1, zeros at fp=0 and fp>=162

#define W2_BYTES  ((size_t)FF*COUT*KTOT*2)           // 11,870,208
#define X2_BYTES  ((size_t)8*TT*FP_*64*2)            // 88,080,384
#define TMP_BYTES ((size_t)8*FF*TT*COUT*2)           // 84,410,368
#define PW_BLOCKS 5796                               // 161*9216/256 u16x4 quads

typedef __bf16 bf16x8 __attribute__((ext_vector_type(8)));
typedef float  f32x4  __attribute__((ext_vector_type(4)));
typedef unsigned short u16x8 __attribute__((ext_vector_type(8)));
typedef unsigned short u16x4 __attribute__((ext_vector_type(4)));
typedef float f4u __attribute__((ext_vector_type(4), aligned(4)));
typedef float f2u __attribute__((ext_vector_type(2), aligned(4)));

__device__ __forceinline__ unsigned short f2bf(float v) {
    union { float f; unsigned int u; } c; c.f = v;
    unsigned int u = c.u + 0x7FFFu + ((c.u >> 16) & 1u);   // RNE
    return (unsigned short)(u >> 16);
}
__device__ __forceinline__ float bf2f(unsigned short h) {
    union { unsigned int u; float f; } c; c.u = (unsigned)h << 16;
    return c.f;
}

// ---- fused prep: blocks [0, PW_BLOCKS) repack weights; rest transpose x ----
__global__ __launch_bounds__(256) void prep_fused(
    const float* __restrict__ ksrc, unsigned short* __restrict__ w2,
    const float* __restrict__ x, unsigned short* __restrict__ x2)
{
    __shared__ unsigned short Xs[64][170];
    int bx = blockIdx.x;
    int tid = threadIdx.x;

    if (bx < PW_BLOCKS) {
        int g  = bx*256 + tid;          // u16x4 index
        int f  = g / 9216;
        int j  = g - f*9216;
        int o  = j / 144;
        int r  = j - o*144;
        int q  = r >> 4;                // tap
        int i4 = (r & 15) * 4;
        u16x4 v;
        #pragma unroll
        for (int e = 0; e < 4; ++e)
            v[e] = f2bf(ksrc[((size_t)(o*64 + i4 + e)*FF + f)*9 + q]);
        *(u16x4*)&w2[(size_t)f*36864 + j*4] = v;
        return;
    }

    int bt = bx - PW_BLOCKS;            // 0..4095
    int b  = bt >> 9;
    int t  = bt & 511;
    const float* xb = x + (size_t)b*CIN*TFSTR + (size_t)t*FF;
    #pragma unroll
    for (int k = 0; k < 21; ++k) {
        int s = tid + k*256;
        if (s < 5184) {                 // 64 i * 81 slots
            int i = s / 81;
            int u = s - i*81;
            const float* p = xb + (size_t)i*TFSTR + 2*u;
            if (u < 80) {
                f2u v = *(const f2u*)p;
                unsigned pk = (unsigned)f2bf(v.x) | ((unsigned)f2bf(v.y) << 16);
                *(unsigned*)&Xs[i][2*u] = pk;
            } else {
                Xs[i][160] = f2bf(*p);
            }
        }
    }
    __syncthreads();
    unsigned short* ob = x2 + (size_t)bt * FP_ * 64;
    #pragma unroll
    for (int k = 0; k < 6; ++k) {
        int s = tid + k*256;
        if (s < 1344) {                 // 168 fp rows * 8 chunks
            int fp = s >> 3;
            int j  = s & 7;
            u16x8 v = {0,0,0,0,0,0,0,0};
            if (fp >= 1 && fp < 162) {
                int f = fp - 1;
                #pragma unroll
                for (int e = 0; e < 8; ++e) v[e] = Xs[j*8 + e][f];
            }
            *(u16x8*)&ob[fp*64 + j*8] = v;
        }
    }
}

// ---- conv: round-3 vehicle (4f x 64o x 64t, 4 waves = o-quarters), but the
// epilogue writes tmp[b][f][t][o] bf16: a 64B line = 32 o for one (f,t) and is
// completed by one wv-pair of the SAME block within one instruction burst ->
// zero partial-line RMW, write bytes halved.
__global__ __launch_bounds__(256, 2) void conv_mfma6(
    const unsigned short* __restrict__ x2, const unsigned short* __restrict__ w2,
    unsigned short* __restrict__ tmp)
{
    int bx  = blockIdx.x;           // 2624 = 8 * 328
    int xcd = bx & 7;
    int s   = bx >> 3;              // 0..327
    int fblk, g;
    if (s < 320) {
        int qd = s >> 5, w = s & 31;
        fblk = qd*4 + (w & 3);      // weight-quad stays L2-hot per XCD
        g    = (w >> 2)*8 + xcd;
    } else {
        fblk = 40;                  // f0=160 (single valid f)
        g    = (s - 320)*8 + xcd;
    }
    int b  = g >> 3;
    int t0 = (g & 7) * 64;
    int f0 = fblk * 4;

    __shared__ alignas(16) unsigned short As[416*64];   // 53,248 B

    int tid = threadIdx.x;
    int wv  = tid >> 6;             // o-quarter
    int l   = tid & 63;
    int lr  = l >> 3;
    int j   = l & 7;

    const unsigned short* zrow = x2 + 167*64;   // guaranteed-zero row

    #pragma unroll
    for (int it = 0; it < 13; ++it) {
        int r0  = wv*8 + it*32;
        int row = r0 + lr;
        int tl  = row / 6;
        int fl  = row - tl*6;
        int gt  = t0 - 1 + tl;
        int fp  = f0 + fl;                      // <= 165 < FP_
        bool ok = (tl < 66) && (gt >= 0) && (gt < TT);
        int key = (tl + fl) & 7;
        const unsigned short* src = ok
            ? x2 + ((((size_t)b*TT + gt)*FP_ + fp)*64 + ((j ^ key) * 8))
            : zrow + j*8;
        __builtin_amdgcn_global_load_lds(
            (const __attribute__((address_space(1))) void*)src,
            (__attribute__((address_space(3))) void*)(As + (size_t)r0*64),
            16, 0, 0);
    }
    __syncthreads();

    int l15 = l & 15;
    int lq  = l >> 4;
    int o   = wv*16 + l15;

    f32x4 acc[4][4] = {};           // [u=f][mf]
    const unsigned short* wb = w2 + ((size_t)f0*COUT + o)*KTOT;
    // (fblk==40: u>=1 weight reads run past w2 into x2 region of d_ws: safe, discarded)

    #pragma unroll
    for (int dm = 0; dm < 3; ++dm) {
        #pragma unroll
        for (int is = 0; is < 2; ++is) {
            int kb = is*32 + lq*8;
            bf16x8 bw[3][4];
            #pragma unroll
            for (int dn = 0; dn < 3; ++dn)
                #pragma unroll
                for (int u = 0; u < 4; ++u)
                    bw[dn][u] = *(const bf16x8*)&wb[(size_t)u*COUT*KTOT + (dm*3 + dn)*64 + kb];
            #pragma unroll
            for (int mf = 0; mf < 4; ++mf) {
                int tl = mf*16 + l15 + dm;
                bf16x8 a6[6];
                #pragma unroll
                for (int v = 0; v < 6; ++v) {
                    int isw = kb ^ (((tl + v) & 7) << 3);
                    a6[v] = *(const bf16x8*)&As[(tl*6 + v)*64 + isw];
                }
                #pragma unroll
                for (int dn = 0; dn < 3; ++dn)
                    #pragma unroll
                    for (int u = 0; u < 4; ++u)
                        acc[u][mf] = __builtin_amdgcn_mfma_f32_16x16x32_bf16(
                            a6[u + dn], bw[dn][u], acc[u][mf], 0, 0, 0);
            }
        }
    }

    // ---- epilogue: tmp[b][f][t][o] bf16, full-line completion inside block ----
    #pragma unroll
    for (int u = 0; u < 4; ++u) {
        int fe = f0 + u;
        if (fe < FF) {                          // block-uniform guard
            size_t tb = ((size_t)b*FF + fe)*TT + t0;
            #pragma unroll
            for (int mf = 0; mf < 4; ++mf)
                #pragma unroll
                for (int rr = 0; rr < 4; ++rr) {
                    int t = mf*16 + lq*4 + rr;
                    tmp[(tb + t)*COUT + o] = f2bf(acc[u][mf][rr]);
                }
        }
    }
}

// ---- finalize: tmp[b][f][t][o] bf16 + bias -> out[b][o][t][f] f32 ----
// block = (b, 4t, 32o): LDS tile 644 rows x 32 (pad 40), dense reads & writes
__global__ __launch_bounds__(256) void finalize(
    const unsigned short* __restrict__ tmp, const float* __restrict__ bias,
    float* __restrict__ out)
{
    int bx = blockIdx.x;            // 2048 = 8 * 128 * 2
    int b  = bx & 7;
    int s  = bx >> 3;               // 0..255
    int tb = s >> 1;
    int oh = s & 1;
    int t0 = tb * 4;
    int o0 = oh * 32;

    __shared__ unsigned short Ld[644*40];       // 51,520 B

    int tid = threadIdx.x;

    // stage: 161 f x 4 t x 4 j u16x8-slots = 2576
    #pragma unroll
    for (int k = 0; k < 11; ++k) {
        int sl = tid + k*256;
        if (sl < 2576) {
            int f = sl >> 4;
            int r = sl & 15;
            int t = r >> 2;
            int j = r & 3;
            const unsigned short* src =
                tmp + (((size_t)b*FF + f)*TT + t0 + t)*COUT + o0 + j*8;
            int row = f*4 + t;
            *(u16x8*)&Ld[row*40 + ((j ^ (f & 3)) << 3)] = *(const u16x8*)src;
        }
    }
    __syncthreads();

    // write: per o_loc, 644 contiguous floats (t0..t0+3 x f0..160) in out
    for (int ol = 0; ol < 32; ++ol) {
        int o = o0 + ol;
        const float* bp = bias + (size_t)o*FF;
        float* op = out + (((size_t)b*COUT + o)*TT + t0)*FF;
        int jo = ol >> 3, o7 = ol & 7;
        #pragma unroll
        for (int k = 0; k < 3; ++k) {
            int r = tid + k*256;
            if (r < 4*FF) {
                int t = r / FF;
                int f = r - t*FF;
                int row = f*4 + t;
                float v = bf2f(Ld[row*40 + ((jo ^ (f & 3)) << 3) + o7]);
                op[r] = v + bp[f];
            }
        }
    }
}

// ---- mid fallback: round-3 kernel, direct strided stores to out ----
__global__ __launch_bounds__(256, 2) void conv_mfma3d(
    const unsigned short* __restrict__ x2, const unsigned short* __restrict__ w2,
    const float* __restrict__ bias, float* __restrict__ out)
{
    int bx  = blockIdx.x;
    int xcd = bx & 7;
    int s   = bx >> 3;
    int fblk, g;
    if (s < 320) {
        int qd = s >> 5, w = s & 31;
        fblk = qd*4 + (w & 3);
        g    = (w >> 2)*8 + xcd;
    } else {
        fblk = 40;
        g    = (s - 320)*8 + xcd;
    }
    int b  = g >> 3;
    int t0 = (g & 7) * 64;
    int f0 = fblk * 4;

    __shared__ alignas(16) unsigned short As[416*64];

    int tid = threadIdx.x;
    int wv  = tid >> 6;
    int l   = tid & 63;
    int lr  = l >> 3;
    int j   = l & 7;

    const unsigned short* zrow = x2 + 167*64;

    #pragma unroll
    for (int it = 0; it < 13; ++it) {
        int r0  = wv*8 + it*32;
        int row = r0 + lr;
        int tl  = row / 6;
        int fl  = row - tl*6;
        int gt  = t0 - 1 + tl;
        int fp  = f0 + fl;
        bool ok = (tl < 66) && (gt >= 0) && (gt < TT);
        int key = (tl + fl) & 7;
        const unsigned short* src = ok
            ? x2 + ((((size_t)b*TT + gt)*FP_ + fp)*64 + ((j ^ key) * 8))
            : zrow + j*8;
        __builtin_amdgcn_global_load_lds(
            (const __attribute__((address_space(1))) void*)src,
            (__attribute__((address_space(3))) void*)(As + (size_t)r0*64),
            16, 0, 0);
    }
    __syncthreads();

    int l15 = l & 15;
    int lq  = l >> 4;
    int o   = wv*16 + l15;

    f32x4 acc[4][4] = {};
    const unsigned short* wb = w2 + ((size_t)f0*COUT + o)*KTOT;

    #pragma unroll
    for (int dm = 0; dm < 3; ++dm) {
        #pragma unroll
        for (int is = 0; is < 2; ++is) {
            int kb = is*32 + lq*8;
            bf16x8 bw[3][4];
            #pragma unroll
            for (int dn = 0; dn < 3; ++dn)
                #pragma unroll
                for (int u = 0; u < 4; ++u)
                    bw[dn][u] = *(const bf16x8*)&wb[(size_t)u*COUT*KTOT + (dm*3 + dn)*64 + kb];
            #pragma unroll
            for (int mf = 0; mf < 4; ++mf) {
                int tl = mf*16 + l15 + dm;
                bf16x8 a6[6];
                #pragma unroll
                for (int v = 0; v < 6; ++v) {
                    int isw = kb ^ (((tl + v) & 7) << 3);
                    a6[v] = *(const bf16x8*)&As[(tl*6 + v)*64 + isw];
                }
                #pragma unroll
                for (int dn = 0; dn < 3; ++dn)
                    #pragma unroll
                    for (int u = 0; u < 4; ++u)
                        acc[u][mf] = __builtin_amdgcn_mfma_f32_16x16x32_bf16(
                            a6[u + dn], bw[dn][u], acc[u][mf], 0, 0, 0);
            }
        }
    }

    size_t rowb = ((size_t)b*COUT + o)*TT + t0;
    if (f0 + 3 <= 160) {
        float bv[4];
        #pragma unroll
        for (int u = 0; u < 4; ++u) bv[u] = bias[o*FF + f0 + u];
        #pragma unroll
        for (int mf = 0; mf < 4; ++mf)
            #pragma unroll
            for (int rr = 0; rr < 4; ++rr) {
                int t = mf*16 + lq*4 + rr;
                f4u v = { acc[0][mf][rr] + bv[0], acc[1][mf][rr] + bv[1],
                          acc[2][mf][rr] + bv[2], acc[3][mf][rr] + bv[3] };
                *(f4u*)(out + (rowb + t)*FF + f0) = v;
            }
    } else {
        float bv0 = bias[o*FF + 160];
        #pragma unroll
        for (int mf = 0; mf < 4; ++mf)
            #pragma unroll
            for (int rr = 0; rr < 4; ++rr) {
                int t = mf*16 + lq*4 + rr;
                out[(rowb + t)*FF + 160] = acc[0][mf][rr] + bv0;
            }
    }
}

// ---- small fallback: stages directly from f32 x; needs only w2 ----
__global__ __launch_bounds__(256) void conv_mfma(
    const float* __restrict__ x, const unsigned short* __restrict__ w2,
    const float* __restrict__ bias, float* __restrict__ out)
{
    int bx = blockIdx.x;
    int r  = bx & 7;
    int q  = bx >> 3;
    int fblk = q % 41;
    int g  = (q / 41) * 8 + r;
    int b  = g >> 3;
    int t0 = (g & 7) * 64;
    int f0 = fblk * 4;

    __shared__ unsigned short Bs[6][66][64];
    int tid = threadIdx.x;

    for (int i = 0; i < 64; i += 4) {
        #pragma unroll
        for (int pp = 0; pp < 2; ++pp) {
            int p = tid + pp*256;
            if (p < 396) {
                int tl = p / 6, fl = p % 6;
                int gt = t0 - 1 + tl;
                int gf = f0 - 1 + fl;
                bool ok = (gt >= 0) && (gt < TT) && (gf >= 0) && (gf < FF);
                const float* xp = x + (((size_t)(b*CIN + i)*TT + gt)*FF + gf);
                float v0 = ok ? xp[0]       : 0.f;
                float v1 = ok ? xp[TFSTR]   : 0.f;
                float v2 = ok ? xp[2*TFSTR] : 0.f;
                float v3 = ok ? xp[3*TFSTR] : 0.f;
                int isw = i ^ (((tl + fl) & 7) << 3);
                ushort4 pk;
                pk.x = f2bf(v0); pk.y = f2bf(v1); pk.z = f2bf(v2); pk.w = f2bf(v3);
                *reinterpret_cast<ushort4*>(&Bs[fl][tl][isw]) = pk;
            }
        }
    }
    __syncthreads();

    int wv = tid >> 6;
    int l  = tid & 63;
    int f  = f0 + wv;
    if (f >= FF) return;

    int l15 = l & 15;
    int lq  = l >> 4;
    f32x4 acc[4][4] = {};
    const unsigned short* wb = w2 + (size_t)f * (COUT * KTOT);

    #pragma unroll
    for (int dm = 0; dm < 3; ++dm)
    #pragma unroll
    for (int dn = 0; dn < 3; ++dn) {
        int fl = wv + dn;
        int kq = (dm*3 + dn) * 64;
        #pragma unroll
        for (int is = 0; is < 2; ++is) {
            int i0 = is*32 + lq*8;
            bf16x8 a[4];
            #pragma unroll
            for (int mf = 0; mf < 4; ++mf) {
                int tl  = mf*16 + l15 + dm;
                int isw = i0 ^ (((tl + fl) & 7) << 3);
                a[mf] = *(const bf16x8*)&Bs[fl][tl][isw];
            }
            int kb = kq + i0;
            #pragma unroll
            for (int nf = 0; nf < 4; ++nf) {
                bf16x8 bfr = *(const bf16x8*)&wb[(size_t)(nf*16 + l15) * KTOT + kb];
                #pragma unroll
                for (int mf = 0; mf < 4; ++mf)
                    acc[mf][nf] = __builtin_amdgcn_mfma_f32_16x16x32_bf16(
                        a[mf], bfr, acc[mf][nf], 0, 0, 0);
            }
        }
    }

    #pragma unroll
    for (int nf = 0; nf < 4; ++nf) {
        int o = nf*16 + l15;
        float bv = bias[o*FF + f];
        size_t obase = (((size_t)b*COUT + o)*TT + t0 + lq*4)*FF + f;
        #pragma unroll
        for (int mf = 0; mf < 4; ++mf)
            #pragma unroll
            for (int rr = 0; rr < 4; ++rr)
                out[obase + (size_t)(mf*16 + rr)*FF] = acc[mf][nf][rr] + bv;
    }
}

extern "C" void kernel_launch(void* const* d_in, const int* in_sizes, int n_in,
                              void* d_out, int out_size, void* d_ws, size_t ws_size,
                              hipStream_t stream)
{
    (void)in_sizes; (void)n_in; (void)out_size;
    const float* x    = (const float*)d_in[0];
    const float* k    = (const float*)d_in[1];
    const float* bias = (const float*)d_in[2];
    float* out = (float*)d_out;
    unsigned short* w2  = (unsigned short*)d_ws;
    unsigned short* x2  = (unsigned short*)((char*)d_ws + W2_BYTES);
    unsigned short* tmp = (unsigned short*)((char*)d_ws + W2_BYTES + X2_BYTES);

    bool big  = (ws_size >= W2_BYTES + X2_BYTES);
    bool big2 = (ws_size >= W2_BYTES + X2_BYTES + TMP_BYTES);

    prep_fused<<<big ? (PW_BLOCKS + 8*TT) : PW_BLOCKS, 256, 0, stream>>>(k, w2, x, x2);

    if (big2) {
        conv_mfma6<<<8*328, 256, 0, stream>>>(x2, w2, tmp);
        finalize<<<2048, 256, 0, stream>>>(tmp, bias, out);
    } else if (big) {
        conv_mfma3d<<<8*328, 256, 0, stream>>>(x2, w2, bias, out);
    } else {
        conv_mfma<<<8*41*8, 256, 0, stream>>>(x, w2, bias, out);
    }
}

// Round 7
// 276.897 us; speedup vs baseline: 2.2367x; 1.1539x over previous
//
#include <hip/hip_runtime.h>
#include <hip/hip_bf16.h>

#define CIN   64
#define COUT  64
#define TT    512
#define FF    161
#define KTOT  576          // 9 * 64
#define TFSTR (TT*FF)      // 82432
#define FP_   168          // padded f dim of X2: fp = f+1, zeros at fp=0 and fp>=162

#define W2_BYTES  ((size_t)FF*COUT*KTOT*2)           // 11,870,208
#define X2_BYTES  ((size_t)8*TT*FP_*64*2)            // 88,080,384
#define TMP_BYTES ((size_t)8*FF*TT*COUT*2)           // 84,410,368
#define PW_BLOCKS 5796                               // 161*9216/256 u16x4 quads

typedef __bf16 bf16x8 __attribute__((ext_vector_type(8)));
typedef float  f32x4  __attribute__((ext_vector_type(4)));
typedef unsigned short u16x8 __attribute__((ext_vector_type(8)));
typedef unsigned short u16x4 __attribute__((ext_vector_type(4)));
typedef unsigned int   u32x2 __attribute__((ext_vector_type(2)));
typedef float f4u __attribute__((ext_vector_type(4), aligned(4)));

__device__ __forceinline__ unsigned short f2bf(float v) {
    union { float f; unsigned int u; } c; c.f = v;
    unsigned int u = c.u + 0x7FFFu + ((c.u >> 16) & 1u);   // RNE
    return (unsigned short)(u >> 16);
}
__device__ __forceinline__ float bf2f(unsigned short h) {
    union { unsigned int u; float f; } c; c.u = (unsigned)h << 16;
    return c.f;
}

// ---- fused prep: blocks [0, PW_BLOCKS) repack weights; rest transpose x ----
__global__ __launch_bounds__(256) void prep_fused(
    const float* __restrict__ ksrc, unsigned short* __restrict__ w2,
    const float* __restrict__ x, unsigned short* __restrict__ x2)
{
    __shared__ unsigned short Xs[64][172];      // 22,016 B; 344B rows (8B aligned)
    int bx = blockIdx.x;
    int tid = threadIdx.x;

    if (bx < PW_BLOCKS) {                       // W2[f][o][k], k=(kh*3+kw)*64+i
        int g  = bx*256 + tid;                  // u16x4 index
        int f  = g / 9216;
        int j  = g - f*9216;
        int o  = j / 144;
        int r  = j - o*144;
        int q  = r >> 4;                        // tap
        int i4 = (r & 15) * 4;
        u16x4 v;
        #pragma unroll
        for (int e = 0; e < 4; ++e)
            v[e] = f2bf(ksrc[((size_t)(o*64 + i4 + e)*FF + f)*9 + q]);
        *(u16x4*)&w2[(size_t)f*36864 + j*4] = v;
        return;
    }

    // x: (b,i,t,f) f32 -> X2[b][t][fp][i] bf16, fp=f+1 (zero-padded halo cols)
    int bt = bx - PW_BLOCKS;                    // 0..4095
    int b  = bt >> 9;
    int t  = bt & 511;
    const float* xb = x + (size_t)b*CIN*TFSTR + (size_t)t*FF;
    #pragma unroll
    for (int k = 0; k < 11; ++k) {
        int s = tid + k*256;
        if (s < 2624) {                         // 64 i * 41 slots (40 f4 + 1 tail)
            int i = s / 41;
            int u = s - i*41;
            const float* p = xb + (size_t)i*TFSTR + 4*u;
            if (u < 40) {
                f4u v = *(const f4u*)p;         // dword-aligned x4 load (gfx9 ok)
                u32x2 pk = { (unsigned)f2bf(v.x) | ((unsigned)f2bf(v.y) << 16),
                             (unsigned)f2bf(v.z) | ((unsigned)f2bf(v.w) << 16) };
                *(u32x2*)&Xs[i][4*u] = pk;      // 8B aligned (344*i + 8u)
            } else {
                Xs[i][160] = f2bf(*p);
            }
        }
    }
    __syncthreads();
    unsigned short* ob = x2 + (size_t)bt * FP_ * 64;
    #pragma unroll
    for (int k = 0; k < 6; ++k) {
        int s = tid + k*256;
        if (s < 1344) {                         // 168 fp rows * 8 chunks
            int fp = s >> 3;
            int j  = s & 7;
            u16x8 v = {0,0,0,0,0,0,0,0};
            if (fp >= 1 && fp < 162) {
                int f = fp - 1;
                #pragma unroll
                for (int e = 0; e < 8; ++e) v[e] = Xs[j*8 + e][f];
            }
            *(u16x8*)&ob[fp*64 + j*8] = v;
        }
    }
}

// ---- conv: 4f x 64o x 64t per block, 4 waves = o-quarters, 2-phase i-split
// pipeline: stage(h0); bar; stage(h1) || compute(is=0); bar; compute(is=1).
// LDS rows r = fl*66+tl (odd tl-parity in r) + 4-slot XOR -> 8cy b128 reads.
// Epilogue: bias fused, tmp[b][f][t][o] bf16 (full-line completion per block).
__global__ __launch_bounds__(256, 3) void conv_mfma7(
    const unsigned short* __restrict__ x2, const unsigned short* __restrict__ w2,
    const float* __restrict__ bias, unsigned short* __restrict__ tmp)
{
    int bx  = blockIdx.x;           // 2624 = 8 * 328
    int xcd = bx & 7;
    int s   = bx >> 3;              // 0..327
    int fblk, g;
    if (s < 320) {
        int qd = s >> 5, w = s & 31;
        fblk = qd*4 + (w & 3);      // weight-quad stays L2-hot per XCD
        g    = (w >> 2)*8 + xcd;
    } else {
        fblk = 40;                  // f0=160 (single valid f)
        g    = (s - 320)*8 + xcd;
    }
    int b  = g >> 3;
    int t0 = (g & 7) * 64;
    int f0 = fblk * 4;

    __shared__ alignas(16) unsigned short As[2][12800];  // 2 x 400 rows x 32 = 51,200 B

    int tid = threadIdx.x;
    int wv  = tid >> 6;             // o-quarter
    int l   = tid & 63;
    int l15 = l & 15;
    int lq  = l >> 4;
    int o   = wv*16 + l15;

    const unsigned short* zrow = x2 + 167*64;   // guaranteed-zero row

    auto stage = [&](int ih) {
        #pragma unroll
        for (int it = 0; it < 7; ++it) {
            int idx = tid + it*256;             // 16B-slot index (wave-uniform cut)
            if (idx < 1600) {                   // 400 rows x 4 slots
                int row = idx >> 2;
                int j   = idx & 3;
                int fl  = row / 66;
                int tl  = row - fl*66;
                int gt  = t0 - 1 + tl;
                int fp  = f0 + fl;              // <= 166 < FP_
                bool ok = (fl < 6) && (gt >= 0) && (gt < TT);
                int key = (tl + fl) & 3;
                const unsigned short* src = ok
                    ? x2 + ((((size_t)b*TT + gt)*FP_ + fp)*64 + ih*32 + ((j ^ key) * 8))
                    : zrow + j*8;
                __builtin_amdgcn_global_load_lds(
                    (const __attribute__((address_space(1))) void*)src,
                    (__attribute__((address_space(3))) void*)(&As[ih][(size_t)(wv*64 + it*256)*8]),
                    16, 0, 0);
            }
        }
    };

    f32x4 acc[4][4] = {};           // [u=f][mf]
    const unsigned short* wb = w2 + ((size_t)f0*COUT + o)*KTOT;
    // (fblk==40: u>=1 weight reads run past w2 into x2 region of d_ws: safe, discarded)

    stage(0);
    __syncthreads();
    stage(1);                       // in flight during is=0 compute

    #pragma unroll
    for (int is = 0; is < 2; ++is) {
        if (is) __syncthreads();    // As[1] ready (vmcnt drained at barrier)
        const unsigned short* bp = As[is];
        int kb = is*32 + lq*8;
        #pragma unroll
        for (int dm = 0; dm < 3; ++dm) {
            bf16x8 bw[3][4];
            #pragma unroll
            for (int dn = 0; dn < 3; ++dn)
                #pragma unroll
                for (int u = 0; u < 4; ++u)
                    bw[dn][u] = *(const bf16x8*)&wb[(size_t)u*COUT*KTOT + (dm*3+dn)*64 + kb];
            #pragma unroll
            for (int mf = 0; mf < 4; ++mf) {
                int tl = mf*16 + l15 + dm;
                bf16x8 a6[6];
                #pragma unroll
                for (int v = 0; v < 6; ++v) {
                    int slot = lq ^ ((tl + v) & 3);
                    a6[v] = *(const bf16x8*)&bp[(size_t)(v*66 + tl)*32 + slot*8];
                }
                #pragma unroll
                for (int dn = 0; dn < 3; ++dn)
                    #pragma unroll
                    for (int u = 0; u < 4; ++u)
                        acc[u][mf] = __builtin_amdgcn_mfma_f32_16x16x32_bf16(
                            a6[u + dn], bw[dn][u], acc[u][mf], 0, 0, 0);
            }
        }
    }

    // ---- epilogue: bias + bf16 -> tmp[b][f][t][o] ----
    #pragma unroll
    for (int u = 0; u < 4; ++u) {
        int fe = f0 + u;
        if (fe < FF) {                          // block-uniform guard
            float bv = bias[o*FF + fe];
            size_t tb = ((size_t)b*FF + fe)*TT + t0;
            #pragma unroll
            for (int mf = 0; mf < 4; ++mf)
                #pragma unroll
                for (int rr = 0; rr < 4; ++rr) {
                    int t = mf*16 + lq*4 + rr;
                    tmp[(tb + t)*COUT + o] = f2bf(acc[u][mf][rr] + bv);
                }
        }
    }
}

// ---- finalize: tmp[b][f][t][o] bf16 -> out[b][o][t][f] f32 (bias already in) ----
// block = (b, 4t, 32o); LDS row = t*FF+f, pad 40 (Δf -> Δbank 20, period-8 spread)
__global__ __launch_bounds__(256) void finalize2(
    const unsigned short* __restrict__ tmp, float* __restrict__ out)
{
    int bx = blockIdx.x;            // 2048 = 8 * 128 * 2
    int b  = bx & 7;
    int s  = bx >> 3;
    int tb = s >> 1;
    int oh = s & 1;
    int t0 = tb * 4;
    int o0 = oh * 32;

    __shared__ unsigned short Ld[644*40];       // 51,520 B

    int tid = threadIdx.x;

    #pragma unroll
    for (int k = 0; k < 11; ++k) {
        int sl = tid + k*256;
        if (sl < 2576) {                        // 161 f x 4 t x 4 j
            int f = sl >> 4;
            int r = sl & 15;
            int t = r >> 2;
            int j = r & 3;
            const unsigned short* src =
                tmp + (((size_t)b*FF + f)*TT + t0 + t)*COUT + o0 + j*8;
            int row = t*FF + f;
            *(u16x8*)&Ld[row*40 + ((j ^ (f & 3)) << 3)] = *(const u16x8*)src;
        }
    }
    __syncthreads();

    for (int ol = 0; ol < 32; ++ol) {
        int o = o0 + ol;
        float* op = out + (((size_t)b*COUT + o)*TT + t0)*FF;
        int jo = ol >> 3, o7 = ol & 7;
        #pragma unroll
        for (int k = 0; k < 3; ++k) {
            int r = tid + k*256;
            if (r < 4*FF) {                     // row == r (t major, f minor)
                int f = r % FF;
                op[r] = bf2f(Ld[r*40 + ((jo ^ (f & 3)) << 3) + o7]);
            }
        }
    }
}

// ---- small fallback: stages directly from f32 x; needs only w2 (12 MB ws) ----
__global__ __launch_bounds__(256) void conv_mfma(
    const float* __restrict__ x, const unsigned short* __restrict__ w2,
    const float* __restrict__ bias, float* __restrict__ out)
{
    int bx = blockIdx.x;
    int r  = bx & 7;
    int q  = bx >> 3;
    int fblk = q % 41;
    int g  = (q / 41) * 8 + r;
    int b  = g >> 3;
    int t0 = (g & 7) * 64;
    int f0 = fblk * 4;

    __shared__ unsigned short Bs[6][66][64];
    int tid = threadIdx.x;

    for (int i = 0; i < 64; i += 4) {
        #pragma unroll
        for (int pp = 0; pp < 2; ++pp) {
            int p = tid + pp*256;
            if (p < 396) {
                int tl = p / 6, fl = p % 6;
                int gt = t0 - 1 + tl;
                int gf = f0 - 1 + fl;
                bool ok = (gt >= 0) && (gt < TT) && (gf >= 0) && (gf < FF);
                const float* xp = x + (((size_t)(b*CIN + i)*TT + gt)*FF + gf);
                float v0 = ok ? xp[0]       : 0.f;
                float v1 = ok ? xp[TFSTR]   : 0.f;
                float v2 = ok ? xp[2*TFSTR] : 0.f;
                float v3 = ok ? xp[3*TFSTR] : 0.f;
                int isw = i ^ (((tl + fl) & 7) << 3);
                ushort4 pk;
                pk.x = f2bf(v0); pk.y = f2bf(v1); pk.z = f2bf(v2); pk.w = f2bf(v3);
                *reinterpret_cast<ushort4*>(&Bs[fl][tl][isw]) = pk;
            }
        }
    }
    __syncthreads();

    int wv = tid >> 6;
    int l  = tid & 63;
    int f  = f0 + wv;
    if (f >= FF) return;

    int l15 = l & 15;
    int lq  = l >> 4;
    f32x4 acc[4][4] = {};
    const unsigned short* wb = w2 + (size_t)f * (COUT * KTOT);

    #pragma unroll
    for (int dm = 0; dm < 3; ++dm)
    #pragma unroll
    for (int dn = 0; dn < 3; ++dn) {
        int fl = wv + dn;
        int kq = (dm*3 + dn) * 64;
        #pragma unroll
        for (int is = 0; is < 2; ++is) {
            int i0 = is*32 + lq*8;
            bf16x8 a[4];
            #pragma unroll
            for (int mf = 0; mf < 4; ++mf) {
                int tl  = mf*16 + l15 + dm;
                int isw = i0 ^ (((tl + fl) & 7) << 3);
                a[mf] = *(const bf16x8*)&Bs[fl][tl][isw];
            }
            int kb = kq + i0;
            #pragma unroll
            for (int nf = 0; nf < 4; ++nf) {
                bf16x8 bfr = *(const bf16x8*)&wb[(size_t)(nf*16 + l15) * KTOT + kb];
                #pragma unroll
                for (int mf = 0; mf < 4; ++mf)
                    acc[mf][nf] = __builtin_amdgcn_mfma_f32_16x16x32_bf16(
                        a[mf], bfr, acc[mf][nf], 0, 0, 0);
            }
        }
    }

    #pragma unroll
    for (int nf = 0; nf < 4; ++nf) {
        int o = nf*16 + l15;
        float bv = bias[o*FF + f];
        size_t obase = (((size_t)b*COUT + o)*TT + t0 + lq*4)*FF + f;
        #pragma unroll
        for (int mf = 0; mf < 4; ++mf)
            #pragma unroll
            for (int rr = 0; rr < 4; ++rr)
                out[obase + (size_t)(mf*16 + rr)*FF] = acc[mf][nf][rr] + bv;
    }
}

extern "C" void kernel_launch(void* const* d_in, const int* in_sizes, int n_in,
                              void* d_out, int out_size, void* d_ws, size_t ws_size,
                              hipStream_t stream)
{
    (void)in_sizes; (void)n_in; (void)out_size;
    const float* x    = (const float*)d_in[0];
    const float* k    = (const float*)d_in[1];
    const float* bias = (const float*)d_in[2];
    float* out = (float*)d_out;
    unsigned short* w2  = (unsigned short*)d_ws;
    unsigned short* x2  = (unsigned short*)((char*)d_ws + W2_BYTES);
    unsigned short* tmp = (unsigned short*)((char*)d_ws + W2_BYTES + X2_BYTES);

    bool big2 = (ws_size >= W2_BYTES + X2_BYTES + TMP_BYTES);

    prep_fused<<<big2 ? (PW_BLOCKS + 8*TT) : PW_BLOCKS, 256, 0, stream>>>(k, w2, x, x2);

    if (big2) {
        conv_mfma7<<<8*328, 256, 0, stream>>>(x2, w2, bias, tmp);
        finalize2<<<2048, 256, 0, stream>>>(tmp, out);
    } else {
        conv_mfma<<<8*41*8, 256, 0, stream>>>(x, w2, bias, out);    // fallback
    }
}